// Round 4
// baseline (82.250 us; speedup 1.0000x reference)
//
#include <hip/hip_runtime.h>
#include <hip/hip_bf16.h>
#include <stdint.h>

#define TOKENS 4096
#define DIN 1024
#define DOUT 1024
#define RANK 8

typedef __attribute__((ext_vector_type(4))) float f32x4;
typedef __attribute__((ext_vector_type(8))) short short8;

__device__ __forceinline__ unsigned short f2bf(float f) {
    union { float f; unsigned u; } v; v.f = f;
    unsigned r = v.u + 0x7FFFu + ((v.u >> 16) & 1u);
    return (unsigned short)(r >> 16);
}

// W [DOUT][DIN] fp32 -> bf16
__global__ __launch_bounds__(256) void k_convert_w(const float* __restrict__ W,
                                                   ushort* __restrict__ Wb) {
    int i = blockIdx.x * 256 + threadIdx.x;
    float4 v = ((const float4*)W)[i];
    ushort4 u;
    u.x = f2bf(v.x); u.y = f2bf(v.y); u.z = f2bf(v.z); u.w = f2bf(v.w);
    ((ushort4*)Wb)[i] = u;
}

// One block per token t:
//   inter[t][r] = dot(x[t,:], B_params[t,r,:])
//   xb[t,:]     = bf16(x[t,:])
__global__ __launch_bounds__(256) void k_inter(const float* __restrict__ x,
                                               const float* __restrict__ Bp,
                                               float* __restrict__ inter,
                                               ushort* __restrict__ xb) {
    const int t = blockIdx.x;
    const int tid = threadIdx.x;
    const int lane = tid & 63, wave = tid >> 6;

    float4 xv = ((const float4*)(x + (size_t)t * DIN))[tid];

    ushort4 u;
    u.x = f2bf(xv.x); u.y = f2bf(xv.y); u.z = f2bf(xv.z); u.w = f2bf(xv.w);
    ((ushort4*)(xb + (size_t)t * DIN))[tid] = u;

    const float4* B4 = (const float4*)(Bp + (size_t)t * RANK * DIN);
    float acc[RANK];
#pragma unroll
    for (int r = 0; r < RANK; ++r) {
        float4 bv = B4[r * 256 + tid];
        acc[r] = xv.x * bv.x + xv.y * bv.y + xv.z * bv.z + xv.w * bv.w;
    }

    __shared__ float part[4][RANK];
#pragma unroll
    for (int r = 0; r < RANK; ++r) {
        float v = acc[r];
#pragma unroll
        for (int off = 32; off > 0; off >>= 1) v += __shfl_xor(v, off, 64);
        if (lane == 0) part[wave][r] = v;
    }
    __syncthreads();
    if (tid < RANK)
        inter[(size_t)t * RANK + tid] =
            part[0][tid] + part[1][tid] + part[2][tid] + part[3][tid];
}

// out[m,o] = bias[o] + sum_k Xb[m,k]*Wb[o,k] + sum_r inter[m,r]*A[m,o,r]
// BM=128 BN=64 BK=64, 4 waves 2x2, wave quadrant 64x32 (4x2 16x16 frags).
// inter tile staged in LDS with stride 9 (kg groups -> distinct banks),
// bias staged in LDS, A_params streamed in the epilogue, out written ONCE.
__global__ __launch_bounds__(256) void k_gemm_fused(const ushort* __restrict__ Xb,
                                                    const ushort* __restrict__ Wb,
                                                    const float* __restrict__ bias,
                                                    const float* __restrict__ inter,
                                                    const float* __restrict__ Ap,
                                                    float* __restrict__ out) {
    __shared__ ushort As[128 * 64];      // [m][k]
    __shared__ ushort Bs[64 * 64];       // [o][k]
    __shared__ float sInter[128 * 9];    // stride-9 padded [mloc][r]
    __shared__ float sBias[64];

    const int tid = threadIdx.x;
    const int lane = tid & 63, wave = tid >> 6;
    const int wm = wave >> 1, wn = wave & 1;
    const int M0 = blockIdx.y * 128;
    const int N0 = blockIdx.x * 64;
    const int col16 = lane & 15;
    const int kg = lane >> 4;

    // Stage inter tile (1024 floats) and bias (64 floats). Ordered by the
    // K-loop's first __syncthreads.
    {
        float4 v = ((const float4*)(inter + (size_t)M0 * RANK))[tid];
        float* p = sInter + (tid >> 1) * 9 + (tid & 1) * 4;
        p[0] = v.x; p[1] = v.y; p[2] = v.z; p[3] = v.w;
        if (tid < 16) ((float4*)sBias)[tid] = ((const float4*)(bias + N0))[tid];
    }

    f32x4 acc[4][2] = {};

    for (int kt = 0; kt < DIN; kt += 64) {
        __syncthreads();
#pragma unroll
        for (int it = 0; it < 4; ++it) {
            int flat = it * 256 + tid;           // 128 rows x 8 chunks
            int row = flat >> 3, ch = flat & 7;
            const ushort* g = Xb + (size_t)(M0 + row) * DIN + kt + ch * 8;
            __builtin_amdgcn_global_load_lds(
                (const __attribute__((address_space(1))) void*)g,
                (__attribute__((address_space(3))) void*)(As + flat * 8), 16, 0, 0);
        }
#pragma unroll
        for (int it = 0; it < 2; ++it) {
            int flat = it * 256 + tid;           // 64 rows x 8 chunks
            int row = flat >> 3, ch = flat & 7;
            const ushort* g = Wb + (size_t)(N0 + row) * DIN + kt + ch * 8;
            __builtin_amdgcn_global_load_lds(
                (const __attribute__((address_space(1))) void*)g,
                (__attribute__((address_space(3))) void*)(Bs + flat * 8), 16, 0, 0);
        }
        asm volatile("s_waitcnt vmcnt(0)" ::: "memory");
        __syncthreads();

#pragma unroll
        for (int ks = 0; ks < 2; ++ks) {
            short8 a[4], b[2];
#pragma unroll
            for (int mf = 0; mf < 4; ++mf)
                a[mf] = *(const short8*)(As + (wm * 64 + mf * 16 + col16) * 64 + ks * 32 + kg * 8);
#pragma unroll
            for (int nf = 0; nf < 2; ++nf)
                b[nf] = *(const short8*)(Bs + (wn * 32 + nf * 16 + col16) * 64 + ks * 32 + kg * 8);
#pragma unroll
            for (int mf = 0; mf < 4; ++mf)
#pragma unroll
                for (int nf = 0; nf < 2; ++nf)
                    acc[mf][nf] = __builtin_amdgcn_mfma_f32_16x16x32_bf16(
                        a[mf], b[nf], acc[mf][nf], 0, 0, 0);
        }
    }

    // Epilogue: out = acc + bias + dot(inter[m,:], A[m,o,:]) — single write.
#pragma unroll
    for (int nf = 0; nf < 2; ++nf) {
        const int oc = wn * 32 + nf * 16 + col16;
        const int o = N0 + oc;
        const float bb = sBias[oc];
#pragma unroll
        for (int mf = 0; mf < 4; ++mf) {
#pragma unroll
            for (int rg = 0; rg < 4; ++rg) {
                const int mloc = wm * 64 + mf * 16 + kg * 4 + rg;
                const int m = M0 + mloc;
                const float4* A8 = (const float4*)(Ap + ((size_t)m * DOUT + o) * RANK);
                float4 a0 = A8[0], a1 = A8[1];
                const float* iv = sInter + mloc * 9;
                float ad = a0.x * iv[0] + a0.y * iv[1] + a0.z * iv[2] + a0.w * iv[3] +
                           a1.x * iv[4] + a1.y * iv[5] + a1.z * iv[6] + a1.w * iv[7];
                out[(size_t)m * DOUT + o] = acc[mf][nf][rg] + bb + ad;
            }
        }
    }
}

extern "C" void kernel_launch(void* const* d_in, const int* in_sizes, int n_in,
                              void* d_out, int out_size, void* d_ws, size_t ws_size,
                              hipStream_t stream) {
    const float* x    = (const float*)d_in[0];
    const float* Ap   = (const float*)d_in[1];
    const float* Bp   = (const float*)d_in[2];
    const float* W    = (const float*)d_in[3];
    const float* bias = (const float*)d_in[4];
    float* out = (float*)d_out;

    // ws: xb (8 MB) | Wb (2 MB) | inter (128 KB)
    ushort* xb = (ushort*)d_ws;
    ushort* Wb = xb + (size_t)TOKENS * DIN;
    float* inter = (float*)(Wb + (size_t)DOUT * DIN);

    hipLaunchKernelGGL(k_convert_w, dim3(DOUT * DIN / 1024), dim3(256), 0, stream, W, Wb);
    hipLaunchKernelGGL(k_inter, dim3(TOKENS), dim3(256), 0, stream, x, Bp, inter, xb);
    hipLaunchKernelGGL(k_gemm_fused, dim3(DOUT / 64, TOKENS / 128), dim3(256), 0, stream,
                       xb, Wb, bias, inter, Ap, out);
}

// Round 5
// 73.410 us; speedup vs baseline: 1.1204x; 1.1204x over previous
//
#include <hip/hip_runtime.h>
#include <hip/hip_bf16.h>
#include <stdint.h>

#define TOKENS 4096
#define DIN 1024
#define DOUT 1024
#define RANK 8

typedef __attribute__((ext_vector_type(4))) float f32x4;
typedef __attribute__((ext_vector_type(8))) short short8;

__device__ __forceinline__ unsigned short f2bf(float f) {
    union { float f; unsigned u; } v; v.f = f;
    unsigned r = v.u + 0x7FFFu + ((v.u >> 16) & 1u);
    return (unsigned short)(r >> 16);
}

// W [DOUT][DIN] fp32 -> bf16
__global__ __launch_bounds__(256) void k_convert_w(const float* __restrict__ W,
                                                   ushort* __restrict__ Wb) {
    int i = blockIdx.x * 256 + threadIdx.x;
    float4 v = ((const float4*)W)[i];
    ushort4 u;
    u.x = f2bf(v.x); u.y = f2bf(v.y); u.z = f2bf(v.z); u.w = f2bf(v.w);
    ((ushort4*)Wb)[i] = u;
}

// One block per token t:
//   inter[t][r] = dot(x[t,:], B_params[t,r,:])
//   xb[t,:]     = bf16(x[t,:])
__global__ __launch_bounds__(256) void k_inter(const float* __restrict__ x,
                                               const float* __restrict__ Bp,
                                               float* __restrict__ inter,
                                               ushort* __restrict__ xb) {
    const int t = blockIdx.x;
    const int tid = threadIdx.x;
    const int lane = tid & 63, wave = tid >> 6;

    float4 xv = ((const float4*)(x + (size_t)t * DIN))[tid];

    ushort4 u;
    u.x = f2bf(xv.x); u.y = f2bf(xv.y); u.z = f2bf(xv.z); u.w = f2bf(xv.w);
    ((ushort4*)(xb + (size_t)t * DIN))[tid] = u;

    const float4* B4 = (const float4*)(Bp + (size_t)t * RANK * DIN);
    float acc[RANK];
#pragma unroll
    for (int r = 0; r < RANK; ++r) {
        float4 bv = B4[r * 256 + tid];
        acc[r] = xv.x * bv.x + xv.y * bv.y + xv.z * bv.z + xv.w * bv.w;
    }

    __shared__ float part[4][RANK];
#pragma unroll
    for (int r = 0; r < RANK; ++r) {
        float v = acc[r];
#pragma unroll
        for (int off = 32; off > 0; off >>= 1) v += __shfl_xor(v, off, 64);
        if (lane == 0) part[wave][r] = v;
    }
    __syncthreads();
    if (tid < RANK)
        inter[(size_t)t * RANK + tid] =
            part[0][tid] + part[1][tid] + part[2][tid] + part[3][tid];
}

// out[m,o] = bias[o] + sum_k Xb[m,k]*Wb[o,k] + sum_r inter[m,r]*A[m,o,r]
// BM=128 BN=64 BK=64, 16 K-iters. The 128MB A_params stream is spread
// ACROSS the K-loop: each iter loads 2 of this thread's 32 output elements'
// A rows (64B/thread), dots with LDS inter, banks result in sums[e][tid]
// (conflict-free, statically indexed in the epilogue). HBM busy during
// MFMA phase instead of a serial epilogue burst.
__global__ __launch_bounds__(256) void k_gemm_fused(const ushort* __restrict__ Xb,
                                                    const ushort* __restrict__ Wb,
                                                    const float* __restrict__ bias,
                                                    const float* __restrict__ inter,
                                                    const float* __restrict__ Ap,
                                                    float* __restrict__ out) {
    __shared__ ushort As[128 * 64];      // 16 KB [m][k]
    __shared__ ushort Bs[64 * 64];       // 8 KB  [o][k]
    __shared__ float sInter[128 * 8];    // 4 KB  flat copy of inter tile
    __shared__ float sBias[64];
    __shared__ float sums[32 * 256];     // 32 KB adapt partials [e][tid]

    const int tid = threadIdx.x;
    const int lane = tid & 63, wave = tid >> 6;
    const int wm = wave >> 1, wn = wave & 1;
    const int M0 = blockIdx.y * 128;
    const int N0 = blockIdx.x * 64;
    const int col16 = lane & 15;
    const int kg = lane >> 4;

    // Stage inter tile (flat: sInter[mloc*8+r]) and bias. Ordered by the
    // K-loop's first __syncthreads.
    ((float4*)sInter)[tid] = ((const float4*)(inter + (size_t)M0 * RANK))[tid];
    if (tid < 16) ((float4*)sBias)[tid] = ((const float4*)(bias + N0))[tid];

    // Per-thread A base: row m = M0 + wm*64 + kg*4, col o = N0 + wn*32 + col16
    const float* Abase = Ap + ((size_t)(M0 + wm * 64 + kg * 4) * DOUT +
                               (N0 + wn * 32 + col16)) * RANK;

    f32x4 acc[4][2] = {};

    for (int it = 0; it < 16; ++it) {
        const int kt = it * 64;
        __syncthreads();
#pragma unroll
        for (int st = 0; st < 4; ++st) {
            int flat = st * 256 + tid;           // 128 rows x 8 chunks
            int row = flat >> 3, ch = flat & 7;
            const ushort* g = Xb + (size_t)(M0 + row) * DIN + kt + ch * 8;
            __builtin_amdgcn_global_load_lds(
                (const __attribute__((address_space(1))) void*)g,
                (__attribute__((address_space(3))) void*)(As + flat * 8), 16, 0, 0);
        }
#pragma unroll
        for (int st = 0; st < 2; ++st) {
            int flat = st * 256 + tid;           // 64 rows x 8 chunks
            int row = flat >> 3, ch = flat & 7;
            const ushort* g = Wb + (size_t)(N0 + row) * DIN + kt + ch * 8;
            __builtin_amdgcn_global_load_lds(
                (const __attribute__((address_space(1))) void*)g,
                (__attribute__((address_space(3))) void*)(Bs + flat * 8), 16, 0, 0);
        }

        // A-stream slice: elements e0=2*it, e0+1  (nf = it>>3, mf = (it>>1)&3,
        // rg = {0,1} or {2,3}). Two consecutive m rows, 32B contiguous each.
        const int nf = it >> 3, mf = (it >> 1) & 3, rg0 = (it & 1) * 2;
        const float* Ae0 = Abase + ((size_t)(mf * 16 + rg0) * DOUT + nf * 16) * RANK;
        const float* Ae1 = Ae0 + (size_t)DOUT * RANK;
        float4 a00 = ((const float4*)Ae0)[0];
        float4 a01 = ((const float4*)Ae0)[1];
        float4 a10 = ((const float4*)Ae1)[0];
        float4 a11 = ((const float4*)Ae1)[1];

        asm volatile("s_waitcnt vmcnt(0)" ::: "memory");
        __syncthreads();

#pragma unroll
        for (int ks = 0; ks < 2; ++ks) {
            short8 a[4], b[2];
#pragma unroll
            for (int m4 = 0; m4 < 4; ++m4)
                a[m4] = *(const short8*)(As + (wm * 64 + m4 * 16 + col16) * 64 + ks * 32 + kg * 8);
#pragma unroll
            for (int n2 = 0; n2 < 2; ++n2)
                b[n2] = *(const short8*)(Bs + (wn * 32 + n2 * 16 + col16) * 64 + ks * 32 + kg * 8);
#pragma unroll
            for (int m4 = 0; m4 < 4; ++m4)
#pragma unroll
                for (int n2 = 0; n2 < 2; ++n2)
                    acc[m4][n2] = __builtin_amdgcn_mfma_f32_16x16x32_bf16(
                        a[m4], b[n2], acc[m4][n2], 0, 0, 0);
        }

        // Dot the 2 A rows with inter (LDS, broadcast within 16-lane groups)
        const int mloc0 = wm * 64 + mf * 16 + kg * 4 + rg0;
        const float4* iv0 = (const float4*)(sInter + mloc0 * 8);
        const float4* iv1 = (const float4*)(sInter + (mloc0 + 1) * 8);
        float4 i00 = iv0[0], i01 = iv0[1], i10 = iv1[0], i11 = iv1[1];
        float d0 = a00.x * i00.x + a00.y * i00.y + a00.z * i00.z + a00.w * i00.w +
                   a01.x * i01.x + a01.y * i01.y + a01.z * i01.z + a01.w * i01.w;
        float d1 = a10.x * i10.x + a10.y * i10.y + a10.z * i10.z + a10.w * i10.w +
                   a11.x * i11.x + a11.y * i11.y + a11.z * i11.z + a11.w * i11.w;
        sums[(it * 2) * 256 + tid] = d0;
        sums[(it * 2 + 1) * 256 + tid] = d1;
    }

    // Epilogue: out = acc + bias + adapt (all static indexing, no global reads)
#pragma unroll
    for (int nf = 0; nf < 2; ++nf) {
        const int oc = wn * 32 + nf * 16 + col16;
        const int o = N0 + oc;
        const float bb = sBias[oc];
#pragma unroll
        for (int mf = 0; mf < 4; ++mf) {
#pragma unroll
            for (int rg = 0; rg < 4; ++rg) {
                const int m = M0 + wm * 64 + mf * 16 + kg * 4 + rg;
                const int e = nf * 16 + mf * 4 + rg;
                out[(size_t)m * DOUT + o] = acc[mf][nf][rg] + bb + sums[e * 256 + tid];
            }
        }
    }
}

extern "C" void kernel_launch(void* const* d_in, const int* in_sizes, int n_in,
                              void* d_out, int out_size, void* d_ws, size_t ws_size,
                              hipStream_t stream) {
    const float* x    = (const float*)d_in[0];
    const float* Ap   = (const float*)d_in[1];
    const float* Bp   = (const float*)d_in[2];
    const float* W    = (const float*)d_in[3];
    const float* bias = (const float*)d_in[4];
    float* out = (float*)d_out;

    // ws: xb (8 MB) | Wb (2 MB) | inter (128 KB)
    ushort* xb = (ushort*)d_ws;
    ushort* Wb = xb + (size_t)TOKENS * DIN;
    float* inter = (float*)(Wb + (size_t)DOUT * DIN);

    hipLaunchKernelGGL(k_convert_w, dim3(DOUT * DIN / 1024), dim3(256), 0, stream, W, Wb);
    hipLaunchKernelGGL(k_inter, dim3(TOKENS), dim3(256), 0, stream, x, Bp, inter, xb);
    hipLaunchKernelGGL(k_gemm_fused, dim3(DOUT / 64, TOKENS / 128), dim3(256), 0, stream,
                       xb, Wb, bias, inter, Ap, out);
}

// Round 6
// 73.287 us; speedup vs baseline: 1.1223x; 1.0017x over previous
//
#include <hip/hip_runtime.h>
#include <hip/hip_bf16.h>
#include <stdint.h>

#define TOKENS 4096
#define DIN 1024
#define DOUT 1024
#define RANK 8
#define BM 128
#define BN 64
#define BK 64

typedef __attribute__((ext_vector_type(4))) float f32x4;
typedef __attribute__((ext_vector_type(8))) short short8;

__device__ __forceinline__ unsigned short f2bf(float f) {
    union { float f; unsigned u; } v; v.f = f;
    unsigned r = v.u + 0x7FFFu + ((v.u >> 16) & 1u);
    return (unsigned short)(r >> 16);
}

// W [DOUT][DIN] fp32 -> bf16
__global__ __launch_bounds__(256) void k_convert_w(const float* __restrict__ W,
                                                   ushort* __restrict__ Wb) {
    int i = blockIdx.x * 256 + threadIdx.x;
    float4 v = ((const float4*)W)[i];
    ushort4 u;
    u.x = f2bf(v.x); u.y = f2bf(v.y); u.z = f2bf(v.z); u.w = f2bf(v.w);
    ((ushort4*)Wb)[i] = u;
}

// One block per token t: inter[t][r] = dot(x[t,:], B[t,r,:]); xb = bf16(x)
__global__ __launch_bounds__(256) void k_inter(const float* __restrict__ x,
                                               const float* __restrict__ Bp,
                                               float* __restrict__ inter,
                                               ushort* __restrict__ xb) {
    const int t = blockIdx.x;
    const int tid = threadIdx.x;
    const int lane = tid & 63, wave = tid >> 6;

    float4 xv = ((const float4*)(x + (size_t)t * DIN))[tid];

    ushort4 u;
    u.x = f2bf(xv.x); u.y = f2bf(xv.y); u.z = f2bf(xv.z); u.w = f2bf(xv.w);
    ((ushort4*)(xb + (size_t)t * DIN))[tid] = u;

    const float4* B4 = (const float4*)(Bp + (size_t)t * RANK * DIN);
    float acc[RANK];
#pragma unroll
    for (int r = 0; r < RANK; ++r) {
        float4 bv = B4[r * 256 + tid];
        acc[r] = xv.x * bv.x + xv.y * bv.y + xv.z * bv.z + xv.w * bv.w;
    }

    __shared__ float part[4][RANK];
#pragma unroll
    for (int r = 0; r < RANK; ++r) {
        float v = acc[r];
#pragma unroll
        for (int off = 32; off > 0; off >>= 1) v += __shfl_xor(v, off, 64);
        if (lane == 0) part[wave][r] = v;
    }
    __syncthreads();
    if (tid < RANK)
        inter[(size_t)t * RANK + tid] =
            part[0][tid] + part[1][tid] + part[2][tid] + part[3][tid];
}

// out[m,o] = bias[o] + Xb@Wb^T (bf16 MFMA) + sum_r inter[m,r]*A[m,o,r]
// Minimum 2-phase pipeline: double-buffered LDS, STAGE(t+1)+A(t) issued at
// top of iter t, vmcnt(0)+raw barrier only AFTER compute. Full K-unroll ->
// adaptation accumulates straight into acc (static indices).
__global__ __launch_bounds__(256) void k_gemm_fused(const ushort* __restrict__ Xb,
                                                    const ushort* __restrict__ Wb,
                                                    const float* __restrict__ bias,
                                                    const float* __restrict__ inter,
                                                    const float* __restrict__ Ap,
                                                    float* __restrict__ out) {
    __shared__ ushort As[2][BM * BK];   // 2 x 16 KB
    __shared__ ushort Bs[2][BN * BK];   // 2 x 8 KB
    __shared__ float sInter[BM * 8];    // 4 KB
    __shared__ float sBias[BN];

    const int tid = threadIdx.x;
    const int lane = tid & 63, wave = tid >> 6;
    const int wm = wave >> 1, wn = wave & 1;

    // XCD-aware bijective swizzle (512 blocks, 512%8==0): each XCD gets 64
    // consecutive swz = 4 M-panels x 16 N-groups -> Xb panel reuse in its L2.
    const int bid = blockIdx.x;
    const int swz = (bid & 7) * 64 + (bid >> 3);
    const int M0 = (swz >> 4) * BM;
    const int N0 = (swz & 15) * BN;

    const int col16 = lane & 15;
    const int kg = lane >> 4;

    // Stage inter tile + bias into LDS.
    ((float4*)sInter)[tid] = ((const float4*)(inter + (size_t)M0 * RANK))[tid];
    if (tid < 16) ((float4*)sBias)[tid] = ((const float4*)(bias + N0))[tid];

    const float* Abase = Ap + ((size_t)(M0 + wm * 64 + kg * 4) * DOUT +
                               (N0 + wn * 32 + col16)) * RANK;

    auto stage = [&](int b, int kt) {
#pragma unroll
        for (int st = 0; st < 4; ++st) {
            int flat = st * 256 + tid;           // 128 rows x 8 chunks
            int row = flat >> 3, ch = flat & 7;
            const ushort* g = Xb + (size_t)(M0 + row) * DIN + kt + ch * 8;
            __builtin_amdgcn_global_load_lds(
                (const __attribute__((address_space(1))) void*)g,
                (__attribute__((address_space(3))) void*)(&As[b][flat * 8]), 16, 0, 0);
        }
#pragma unroll
        for (int st = 0; st < 2; ++st) {
            int flat = st * 256 + tid;           // 64 rows x 8 chunks
            int row = flat >> 3, ch = flat & 7;
            const ushort* g = Wb + (size_t)(N0 + row) * DIN + kt + ch * 8;
            __builtin_amdgcn_global_load_lds(
                (const __attribute__((address_space(1))) void*)g,
                (__attribute__((address_space(3))) void*)(&Bs[b][flat * 8]), 16, 0, 0);
        }
    };

    // Prologue: stage tile 0; make sInter/sBias + buf0 visible.
    stage(0, 0);
    asm volatile("s_waitcnt vmcnt(0) lgkmcnt(0)" ::: "memory");
    __builtin_amdgcn_s_barrier();

    f32x4 acc[4][2] = {};

#pragma unroll
    for (int it = 0; it < 16; ++it) {
        const int cur = it & 1;
        if (it < 15) stage(cur ^ 1, (it + 1) * BK);

        // A-slice for output elements e = 2*it, 2*it+1 (static after unroll).
        const int nf = it >> 3, mf = (it >> 1) & 3, rg0 = (it & 1) * 2;
        const float* Ae0 = Abase + ((size_t)(mf * 16 + rg0) * DOUT + nf * 16) * RANK;
        const float* Ae1 = Ae0 + (size_t)DOUT * RANK;
        float4 a00 = ((const float4*)Ae0)[0];
        float4 a01 = ((const float4*)Ae0)[1];
        float4 a10 = ((const float4*)Ae1)[0];
        float4 a11 = ((const float4*)Ae1)[1];

        // MFMA on buf[cur] (staged last iter; compiler inserts lgkm waits).
#pragma unroll
        for (int ks = 0; ks < 2; ++ks) {
            short8 a[4], b[2];
#pragma unroll
            for (int m4 = 0; m4 < 4; ++m4)
                a[m4] = *(const short8*)(&As[cur][(wm * 64 + m4 * 16 + col16) * BK + ks * 32 + kg * 8]);
#pragma unroll
            for (int n2 = 0; n2 < 2; ++n2)
                b[n2] = *(const short8*)(&Bs[cur][(wn * 32 + n2 * 16 + col16) * BK + ks * 32 + kg * 8]);
#pragma unroll
            for (int m4 = 0; m4 < 4; ++m4)
#pragma unroll
                for (int n2 = 0; n2 < 2; ++n2)
                    acc[m4][n2] = __builtin_amdgcn_mfma_f32_16x16x32_bf16(
                        a[m4], b[n2], acc[m4][n2], 0, 0, 0);
        }

        // Adaptation dot (A regs consumed after MFMA; waits auto-inserted),
        // accumulated straight into acc at static indices.
        const int mloc0 = wm * 64 + mf * 16 + kg * 4 + rg0;
        const float4* iv0 = (const float4*)(sInter + mloc0 * 8);
        const float4* iv1 = (const float4*)(sInter + (mloc0 + 1) * 8);
        float4 i00 = iv0[0], i01 = iv0[1], i10 = iv1[0], i11 = iv1[1];
        float d0 = a00.x * i00.x + a00.y * i00.y + a00.z * i00.z + a00.w * i00.w +
                   a01.x * i01.x + a01.y * i01.y + a01.z * i01.z + a01.w * i01.w;
        float d1 = a10.x * i10.x + a10.y * i10.y + a10.z * i10.z + a10.w * i10.w +
                   a11.x * i11.x + a11.y * i11.y + a11.z * i11.z + a11.w * i11.w;
        acc[mf][nf][rg0] += d0;
        acc[mf][nf][rg0 + 1] += d1;

        // End of iter: drain STAGE(t+1), then barrier (reads of buf[cur] are
        // complete per-wave by MFMA consumption -> safe to overwrite next iter).
        asm volatile("s_waitcnt vmcnt(0)" ::: "memory");
        __builtin_amdgcn_s_barrier();
    }

    // Epilogue: single coherent write of out.
#pragma unroll
    for (int nf = 0; nf < 2; ++nf) {
        const int oc = wn * 32 + nf * 16 + col16;
        const int o = N0 + oc;
        const float bb = sBias[oc];
#pragma unroll
        for (int mf = 0; mf < 4; ++mf) {
#pragma unroll
            for (int rg = 0; rg < 4; ++rg) {
                const int m = M0 + wm * 64 + mf * 16 + kg * 4 + rg;
                out[(size_t)m * DOUT + o] = acc[mf][nf][rg] + bb;
            }
        }
    }
}

extern "C" void kernel_launch(void* const* d_in, const int* in_sizes, int n_in,
                              void* d_out, int out_size, void* d_ws, size_t ws_size,
                              hipStream_t stream) {
    const float* x    = (const float*)d_in[0];
    const float* Ap   = (const float*)d_in[1];
    const float* Bp   = (const float*)d_in[2];
    const float* W    = (const float*)d_in[3];
    const float* bias = (const float*)d_in[4];
    float* out = (float*)d_out;

    // ws: xb (8 MB) | Wb (2 MB) | inter (128 KB)
    ushort* xb = (ushort*)d_ws;
    ushort* Wb = xb + (size_t)TOKENS * DIN;
    float* inter = (float*)(Wb + (size_t)DOUT * DIN);

    hipLaunchKernelGGL(k_convert_w, dim3(DOUT * DIN / 1024), dim3(256), 0, stream, W, Wb);
    hipLaunchKernelGGL(k_inter, dim3(TOKENS), dim3(256), 0, stream, x, Bp, inter, xb);
    hipLaunchKernelGGL(k_gemm_fused, dim3((TOKENS / BM) * (DOUT / BN)), dim3(256), 0, stream,
                       xb, Wb, bias, inter, Ap, out);
}